// Round 10
// baseline (173.815 us; speedup 1.0000x reference)
//
#include <hip/hip_runtime.h>
#include <math.h>

// Problem constants
#define Bn    64
#define Cn    3
#define IMG   224
#define PLANE (IMG*IMG)      // 50176
#define C1    6
#define P1    110            // conv1(220) + maxpool2 -> 110
#define NVALID (106*106)     // 11236
#define Hh    32
#define Ww    64
#define UPR   10
#define UPT   10
#define Hg    (Hh*UPR)       // 320
#define Wg    (Ww*UPT)       // 640
#define POOLED_SIZE (Bn*Cn*Hh*Ww)   // 393216
#define NCHUNK 28            // 28 chunks x 4 pooled rows = 112 >= 110
#define PSTRIDE 152          // padded 150-float partial slot
#define ROWB  (IMG*8)        // 1792 B: one NHWC4-f16 row
#define TPB1  448            // 7 waves: 14 strips / 7 = 2 each

typedef unsigned short u16;
typedef unsigned int u32;
typedef unsigned long long ull;
typedef _Float16 h8v __attribute__((ext_vector_type(8)));   // 8 f16 MFMA frag
typedef float f4v __attribute__((ext_vector_type(4)));      // 16x16 MFMA acc

// workspace: partials | wt | af | sincos tab | radii | x4h (f16 NHWC4)
#define PART_FLOATS ((size_t)Bn * NCHUNK * PSTRIDE)     // 272,384
#define WT_OFF      PART_FLOATS                         // 272,384 (128 f)
#define AF_OFF_F    (PART_FLOATS + Bn * 2)              // 272,512 (1280 f)
#define SC_OFF_F    (AF_OFF_F + 1280)                   // 273,792 (1280 f)
#define RAD_OFF_F   (SC_OFF_F + 1280)                   // 275,072 (20480 f)
#define X4H_OFF_F   (RAD_OFF_F + (size_t)Bn * Hg)       // 295,552 (byte%16==0)
#define X4B_U16     ((size_t)Bn * PLANE * 4)
#define WS_NEEDED   ((size_t)X4H_OFF_F * 4 + X4B_U16 * 2)

__device__ __forceinline__ unsigned hpack(float a, float b) {
    union { _Float16 h; u16 u; } x, y;
    x.h = (_Float16)a; y.h = (_Float16)b;
    return (unsigned)x.u | ((unsigned)y.u << 16);
}
__device__ __forceinline__ u16 f16b(float f) {
    union { _Float16 h; u16 u; } c; c.h = (_Float16)f; return c.u;
}
__device__ __forceinline__ float h2lo(unsigned v) {
    union { _Float16 h; u16 u; } c; c.u = (u16)(v & 0xffffu); return (float)c.h;
}
__device__ __forceinline__ float h2hi(unsigned v) {
    union { _Float16 h; u16 u; } c; c.u = (u16)(v >> 16); return (float)c.h;
}

// group-local broadcast: read lane (group_base + idx) of a 16-lane group
#define GSHFL(v, idx) __shfl((v), (lane & 48) + (idx), 64)

// -------------------------------------------------------------------------
// K0: prebuild MFMA A-fragments (k = ic + 4*kx) + the 640-entry sin/cos
// table (angle depends only on tid -> identical for all 2048 k3 blocks).
// -------------------------------------------------------------------------
__global__ __launch_bounds__(64) void k0_prep(
    const float* __restrict__ w1, u16* __restrict__ af,
    float* __restrict__ sctab)
{
    const int tid = threadIdx.x;
    const int n = tid & 15, g = tid >> 4;
    #pragma unroll
    for (int ky = 0; ky < 5; ++ky) {
        #pragma unroll
        for (int j = 0; j < 8; ++j) {
            const int k = g * 8 + j, ic = k & 3, kx = k >> 2;
            float w = 0.0f;
            if (n < C1 && ic < 3 && kx < 5)
                w = w1[((n * 3 + ic) * 5 + ky) * 5 + kx];
            af[(ky * 64 + tid) * 8 + j] = f16b(w);
        }
    }
    #pragma unroll
    for (int k = 0; k < 10; ++k) {
        const int t = tid + k * 64;           // 0..639
        const float angle = 6.283185307179586f * (float)t / (float)Wg;
        sctab[t * 2 + 0] = sinf(angle);
        sctab[t * 2 + 1] = cosf(angle);
    }
}

// -------------------------------------------------------------------------
// KA: pure-streaming fp32 NCHW -> f16 NHWC4 pack (read 25.7MB, write 12.9MB
// at memcpy-class BW). 802,816 items (4px each), 3136 x 256 exact.
// -------------------------------------------------------------------------
__global__ __launch_bounds__(256) void kA_pack(
    const float* __restrict__ x, u16* __restrict__ x4h)
{
    const int i = blockIdx.x * 256 + threadIdx.x;   // 0..802815
    const int b  = i / (PLANE / 4);
    const int p4 = i - b * (PLANE / 4);
    const float* xb = x + (size_t)b * 3 * PLANE + p4 * 4;
    const float4 c0 = *(const float4*)(xb);
    const float4 c1 = *(const float4*)(xb + PLANE);
    const float4 c2 = *(const float4*)(xb + 2 * PLANE);
    uint4 W0, W1;
    W0.x = hpack(c0.x, c1.x);  W0.y = hpack(c2.x, 0.0f);
    W0.z = hpack(c0.y, c1.y);  W0.w = hpack(c2.y, 0.0f);
    W1.x = hpack(c0.z, c1.z);  W1.y = hpack(c2.z, 0.0f);
    W1.z = hpack(c0.w, c1.w);  W1.w = hpack(c2.w, 0.0f);
    u16* ob = x4h + ((size_t)b * PLANE + p4 * 4) * 4;
    *(uint4*)(ob)     = W0;
    *(uint4*)(ob + 8) = W1;
}

// -------------------------------------------------------------------------
// KB: conv1 via MFMA with ASYNC global->LDS staging (global_load_lds x16B).
// R9-verified: dropped k1 out of the top-5 (<42us vs 58-67 for all prior
// k1 variants). Conv/pool/window-sum body identical to R5.
// -------------------------------------------------------------------------
__global__ __launch_bounds__(TPB1) void kB_conv(
    const u16* __restrict__ x4h,      // (B,224,224,4) f16
    const u16* __restrict__ af,       // prebuilt A-frags (5,64,8) f16
    const float* __restrict__ b1f,    // (6,)
    float* __restrict__ partial)      // (B,28,PSTRIDE)
{
    __shared__ __attribute__((aligned(16))) unsigned char xs[12 * ROWB];
    __shared__ float rowR[7][C1][4];
    __shared__ float edgeLo[4][C1][4];
    __shared__ float edgeHi[4][C1][4];

    const int b     = blockIdx.x;
    const int chunk = blockIdx.y;
    const int tid   = threadIdx.x;
    const int wid   = tid >> 6;
    const int lane  = tid & 63;
    const int n     = lane & 15;
    const int g     = lane >> 4;
    const int gy0   = chunk * 8;

    // tail chunk 27: only 8 valid rows (gy 216..223); zero LDS rows 8..11
    const int nInst = (chunk == NCHUNK - 1) ? 14 : 21;   // 1024B insts
    if (chunk == NCHUNK - 1)
        *(uint4*)(xs + 8 * ROWB + tid * 16) = (uint4){0u, 0u, 0u, 0u};

    // issue async copies: wave w owns insts {3w, 3w+1, 3w+2}
    {
        const char* gbase = (const char*)x4h
                          + ((size_t)b * PLANE + (size_t)gy0 * IMG) * 8;
        #pragma unroll
        for (int k = 0; k < 3; ++k) {
            const int j = wid * 3 + k;            // wave-uniform
            if (j < nInst) {
                const char* gp = gbase + j * 1024 + lane * 16;
                __builtin_amdgcn_global_load_lds(
                    (const __attribute__((address_space(1))) u32*)gp,
                    (__attribute__((address_space(3))) u32*)(xs + j * 1024),
                    16, 0, 0);
            }
        }
    }

    // A-frags (coalesced 16B loads, overlap with in-flight copies) + bias
    h8v a[5];
    #pragma unroll
    for (int ky = 0; ky < 5; ++ky)
        a[ky] = *(const h8v*)(af + (ky * 64 + lane) * 8);
    f4v binit;
    #pragma unroll
    for (int e = 0; e < 4; ++e) {
        const int oc = g * 4 + e;
        binit[e] = (oc < C1) ? b1f[oc] : 0.0f;
    }

    __syncthreads();   // drains vmcnt -> xs ready

    float colsum[4][4];
    #pragma unroll
    for (int py = 0; py < 4; ++py)
        #pragma unroll
        for (int e = 0; e < 4; ++e) colsum[py][e] = 0.0f;

    #pragma unroll
    for (int si = 0; si < 2; ++si) {
        const int s = wid * 2 + si;         // strip: conv cols s*16..s*16+15
        const unsigned sByte = (unsigned)(s * 128 + n * 8 + g * 16);

        f4v acc[8];
        #pragma unroll
        for (int q = 0; q < 8; ++q) acc[q] = binit;

        #pragma unroll
        for (int r = 0; r < 12; ++r) {
            h8v bf;
            const unsigned char* bp = xs + r * ROWB + sByte;
            ((ull*)&bf)[0] = *(const ull*)bp;
            ((ull*)&bf)[1] = *(const ull*)(bp + 8);
            #pragma unroll
            for (int ky = 0; ky < 5; ++ky) {
                const int q = r - ky;
                if (q >= 0 && q < 8)
                    acc[q] = __builtin_amdgcn_mfma_f32_16x16x32_f16(
                        a[ky], bf, acc[q], 0, 0, 0);
            }
        }

        // maxpool 2x2 + edge capture + col accumulation
        #pragma unroll
        for (int py = 0; py < 4; ++py) {
            #pragma unroll
            for (int e = 0; e < 4; ++e) {
                float t = fmaxf(acc[2 * py][e], acc[2 * py + 1][e]);
                t = fmaxf(t, __shfl_xor(t, 1, 64));
                if (s == 13 && n >= 12) t = 0.0f;     // junk cols 110,111
                colsum[py][e] += t;
                const int oc = g * 4 + e;
                if (s == 0) {                          // pooled cols 0..3
                    const float c0 = GSHFL(t, 0), c1 = GSHFL(t, 2);
                    const float c2 = GSHFL(t, 4), c3 = GSHFL(t, 6);
                    const float S1 = c0, S2 = S1 + c1, S3 = S2 + c2, S4 = S3 + c3;
                    const float sv = (n == 0) ? S1 : (n == 1) ? S2
                                   : (n == 2) ? S3 : S4;
                    if (n < 4 && oc < C1) edgeLo[py][oc][n] = sv;
                }
                if (s == 13) {                         // pooled cols 106..109
                    const float d109 = GSHFL(t, 10), d108 = GSHFL(t, 8);
                    const float d107 = GSHFL(t, 6),  d106 = GSHFL(t, 4);
                    const float U1 = d109, U2 = U1 + d108, U3 = U2 + d107,
                                U4 = U3 + d106;
                    const float uv = (n == 0) ? U1 : (n == 1) ? U2
                                   : (n == 2) ? U3 : U4;
                    if (n < 4 && oc < C1) edgeHi[py][oc][n] = uv;
                }
            }
        }
    }

    // per-wave row sums
    #pragma unroll
    for (int py = 0; py < 4; ++py) {
        #pragma unroll
        for (int e = 0; e < 4; ++e) {
            float v = colsum[py][e];
            v += __shfl_xor(v, 2, 64);
            v += __shfl_xor(v, 4, 64);
            v += __shfl_xor(v, 8, 64);
            const int oc = g * 4 + e;
            if (n == 0 && oc < C1) rowR[wid][oc][py] = v;
        }
    }
    __syncthreads();

    // final: slot(oc,ky,kx) = sum_py valid(py,ky) * (rowsum - S_kx - U_{4-kx})
    if (tid < 150) {
        const int oc = tid / 25;
        const int rem = tid - oc * 25;
        const int ky = rem / 5, kx = rem - ky * 5;
        float total = 0.0f;
        #pragma unroll
        for (int py = 0; py < 4; ++py) {
            const int y = chunk * 4 + py;
            const bool valid = (y < P1) && ((unsigned)(y - ky) <= 105u);
            float v = rowR[0][oc][py] + rowR[1][oc][py] + rowR[2][oc][py]
                    + rowR[3][oc][py] + rowR[4][oc][py] + rowR[5][oc][py]
                    + rowR[6][oc][py];
            if (kx > 0) v -= edgeLo[py][oc][kx - 1];
            if (kx < 4) v -= edgeHi[py][oc][3 - kx];
            total += valid ? v : 0.0f;
        }
        partial[((size_t)b * NCHUNK + chunk) * PSTRIDE + tid] = total;
    }
}

// -------------------------------------------------------------------------
// K2: head (wsum -> feat -> fc1 -> fc2 -> wt) AND the full 320-entry radii
// table per image: radii[b][t] = exp(start + dr*t/(Hg-1)). Moves ALL
// transcendentals out of k3's 1.3M threads into 64 blocks.
// -------------------------------------------------------------------------
__global__ __launch_bounds__(256) void k2_head(
    const float* __restrict__ partial, const float* __restrict__ w2,
    const float* __restrict__ b2, const float* __restrict__ fc1w,
    const float* __restrict__ fc1b, const float* __restrict__ fc2w,
    const float* __restrict__ fc2b, const float* __restrict__ ltp,
    float* __restrict__ wt_ws, float* __restrict__ radii,
    float* __restrict__ out)
{
    const int b = blockIdx.x;
    const int tid = threadIdx.x;
    __shared__ float wsb[150];
    __shared__ float sfeat[16];
    __shared__ float sh[8];
    __shared__ float sSS[2];          // start, dr

    if (tid < 150) {
        const float* p = partial + (size_t)b * NCHUNK * PSTRIDE + tid;
        float s = 0.0f;
        #pragma unroll
        for (int c = 0; c < NCHUNK; ++c) s += p[c * PSTRIDE];
        wsb[tid] = s;
    }
    __syncthreads();
    if (tid < 16) {
        float s = 0.0f;
        for (int j = 0; j < 150; ++j) s += w2[tid * 150 + j] * wsb[j];
        sfeat[tid] = b2[tid] + s * (1.0f / (float)NVALID);
    }
    __syncthreads();
    if (tid < 8) {
        float s = fc1b[tid];
        #pragma unroll
        for (int j = 0; j < 16; ++j) s += fc1w[tid * 16 + j] * sfeat[j];
        sh[tid] = fmaxf(s, 0.0f);
    }
    __syncthreads();
    if (tid < 2) {
        float s = fc2b[tid];
        #pragma unroll
        for (int j = 0; j < 8; ++j) s += fc2w[tid * 8 + j] * sh[j];
        float sig = (s >= 0.0f) ? (1.0f / (1.0f + expf(-s)))
                                : (expf(s) / (1.0f + expf(s)));
        const float wgt = 5.0f * sig;
        wt_ws[b * 2 + tid] = wgt;
        out[POOLED_SIZE + b * 2 + tid] = wgt;
    }
    __syncthreads();
    if (tid == 0) {
        const float start = logf(0.01f * wt_ws[b * 2 + 0]);
        const float stop  = logf(0.6f  * wt_ws[b * 2 + 1]);
        sSS[0] = start; sSS[1] = stop - start;
    }
    __syncthreads();
    {
        const float start = sSS[0], dr = sSS[1];
        #pragma unroll
        for (int k = 0; k < 2; ++k) {
            const int t = tid + k * 256;
            if (t < Hg)
                radii[(size_t)b * Hg + t] =
                    expf(start + dr * ((float)t * (1.0f / (float)(Hg - 1))));
        }
    }
}

// -------------------------------------------------------------------------
// Clamp-coordinate sampling (equivalent to corner-clamp border mode).
// -------------------------------------------------------------------------
__device__ __forceinline__ void sample_coords(
    float gxn, float gyn, int& x0, int& y0, float& wx, float& wy)
{
    float ix = ((gxn + 1.0f) * (float)IMG - 1.0f) * 0.5f;
    float iy = ((gyn + 1.0f) * (float)IMG - 1.0f) * 0.5f;
    ix = fminf(fmaxf(ix, 0.0f), (float)(IMG - 1));
    iy = fminf(fmaxf(iy, 0.0f), (float)(IMG - 1));
    x0 = (int)ix; if (x0 > IMG - 2) x0 = IMG - 2;
    y0 = (int)iy; if (y0 > IMG - 2) y0 = IMG - 2;
    wx = ix - (float)x0;
    wy = iy - (float)y0;
}

// -------------------------------------------------------------------------
// K3 (f16 NHWC4, table-driven): NO transcendentals, NO head — sin/cos from
// k0's table, radii from k2's table (block-uniform scalar loads). Pure
// coords + gathers + FMA. 5-sample gather batches (10 loads in flight,
// VGPR <=48 keeps 8 waves/SIMD). XCD-affinity: b = (L&7)+8*(q>>5).
// -------------------------------------------------------------------------
__global__ __launch_bounds__(640) void k3_sample(
    const u16* __restrict__ x4h,      // (B,224,224,4) f16
    const float* __restrict__ ltp,
    const float* __restrict__ sctab,  // (640,2) sin/cos
    const float* __restrict__ radii,  // (B,320)
    float* __restrict__ out)
{
    __shared__ float part[3 * Wg];

    const int L = blockIdx.x;         // 0..2047
    const int q = L >> 3;             // 0..255
    const int h = q & 31;
    const int b = (L & 7) + 8 * (q >> 5);
    const int tid = threadIdx.x;

    const float l0 = ltp[b * 2 + 0];
    const float l1 = ltp[b * 2 + 1];
    const float2 sc = *(const float2*)(sctab + tid * 2);
    const float sn = sc.x, cs = sc.y;

    const float* rad = radii + (size_t)b * Hg + h * UPR;
    const u16* xb4 = x4h + (size_t)b * PLANE * 4;

    int xi[UPR], yi[UPR];
    float wxa[UPR], wya[UPR];
    #pragma unroll
    for (int i = 0; i < UPR; ++i) {
        const float ri = rad[i];      // block-uniform (s_load broadcast)
        sample_coords(ri * sn + l0, ri * cs + l1, xi[i], yi[i], wxa[i], wya[i]);
    }

    float acc0 = 0.0f, acc1 = 0.0f, acc2 = 0.0f;
    #pragma unroll
    for (int bb = 0; bb < 2; ++bb) {
        uint4 R0[5], R1[5];
        #pragma unroll
        for (int i = 0; i < 5; ++i) {           // 10 gathers in flight
            const int sI = bb * 5 + i;
            const u16* base = xb4 + ((size_t)(yi[sI] * IMG + xi[sI])) * 4;
            R0[i] = *(const uint4*)(base);
            R1[i] = *(const uint4*)(base + IMG * 4);
        }
        #pragma unroll
        for (int i = 0; i < 5; ++i) {
            const int sI = bb * 5 + i;
            const float wx = wxa[sI], wy = wya[sI];
            const float wx0 = 1.0f - wx, wy0 = 1.0f - wy;
            const float w00 = wx0 * wy0, w01 = wx * wy0;
            const float w10 = wx0 * wy,  w11 = wx * wy;
            acc0 += w00*h2lo(R0[i].x) + w01*h2lo(R0[i].z)
                  + w10*h2lo(R1[i].x) + w11*h2lo(R1[i].z);
            acc1 += w00*h2hi(R0[i].x) + w01*h2hi(R0[i].z)
                  + w10*h2hi(R1[i].x) + w11*h2hi(R1[i].z);
            acc2 += w00*h2lo(R0[i].y) + w01*h2lo(R0[i].w)
                  + w10*h2lo(R1[i].y) + w11*h2lo(R1[i].w);
        }
    }
    part[0 * Wg + tid] = acc0;
    part[1 * Wg + tid] = acc1;
    part[2 * Wg + tid] = acc2;
    __syncthreads();

    if (tid < Cn * Ww) {
        const int c = tid / Ww;
        const int w = tid % Ww;
        const float* p = part + c * Wg + w * UPT;
        float s = 0.0f;
        #pragma unroll
        for (int j = 0; j < UPT; ++j) s += p[j];
        out[(((size_t)b * Cn + c) * Hh + h) * Ww + w] = s * (1.0f / (UPR * UPT));
    }
}

// -------------------------------------------------------------------------
// Fallback path (ws too small): R6-style fp32-staged conv + fp32 sampling.
// -------------------------------------------------------------------------
__global__ __launch_bounds__(TPB1) void k1_legacy(
    const float* __restrict__ x, const float* __restrict__ w1,
    const float* __restrict__ b1, float* __restrict__ partial)
{
    __shared__ __attribute__((aligned(16))) unsigned char xs[12 * ROWB + 128];
    __shared__ __attribute__((aligned(16))) _Float16 sa[5][64][8];
    __shared__ float rowR[7][C1][4];
    __shared__ float edgeLo[4][C1][4];
    __shared__ float edgeHi[4][C1][4];

    const int b     = blockIdx.x;
    const int chunk = blockIdx.y;
    const int tid   = threadIdx.x;
    const int wid   = tid >> 6;
    const int lane  = tid & 63;
    const int n     = lane & 15;
    const int g     = lane >> 4;
    const int gy0   = chunk * 8;
    const float* xb = x + (size_t)b * (Cn * PLANE);

    if (wid == 0) {
        #pragma unroll
        for (int ky = 0; ky < 5; ++ky) {
            #pragma unroll
            for (int j = 0; j < 8; ++j) {
                const int kmem = g * 8 + j;
                const int ic = kmem & 3, kx = kmem >> 2;
                float w = 0.0f;
                if (n < C1 && ic < 3 && kx < 5)
                    w = w1[((n * 3 + ic) * 5 + ky) * 5 + kx];
                sa[ky][lane][j] = (_Float16)w;
            }
        }
    } else {
        for (int i = tid - 64; i < 12 * 112; i += TPB1 - 64) {
            const int r = i / 112;
            const int p = i - r * 112;
            const int gy = gy0 + r;
            uint4 U; U.x = U.y = U.z = U.w = 0u;
            if (gy < IMG) {
                const float2 v0 = *(const float2*)(xb + 0 * PLANE + gy * IMG + 2 * p);
                const float2 v1 = *(const float2*)(xb + 1 * PLANE + gy * IMG + 2 * p);
                const float2 v2 = *(const float2*)(xb + 2 * PLANE + gy * IMG + 2 * p);
                U.x = hpack(v0.x, v1.x);
                U.y = hpack(v2.x, 0.0f);
                U.z = hpack(v0.y, v1.y);
                U.w = hpack(v2.y, 0.0f);
            }
            *(uint4*)(xs + r * ROWB + p * 16) = U;
        }
    }
    __syncthreads();

    h8v a[5];
    #pragma unroll
    for (int ky = 0; ky < 5; ++ky) a[ky] = *(const h8v*)&sa[ky][lane][0];
    f4v binit;
    #pragma unroll
    for (int e = 0; e < 4; ++e) {
        const int oc = g * 4 + e;
        binit[e] = (oc < C1) ? b1[oc] : 0.0f;
    }

    float colsum[4][4];
    #pragma unroll
    for (int py = 0; py < 4; ++py)
        #pragma unroll
        for (int e = 0; e < 4; ++e) colsum[py][e] = 0.0f;

    #pragma unroll
    for (int si = 0; si < 2; ++si) {
        const int s = wid * 2 + si;
        const unsigned sByte = (unsigned)(s * 128 + n * 8 + g * 16);
        f4v acc[8];
        #pragma unroll
        for (int q = 0; q < 8; ++q) acc[q] = binit;
        #pragma unroll
        for (int r = 0; r < 12; ++r) {
            h8v bf;
            const unsigned char* bp = xs + r * ROWB + sByte;
            ((ull*)&bf)[0] = *(const ull*)bp;
            ((ull*)&bf)[1] = *(const ull*)(bp + 8);
            #pragma unroll
            for (int ky = 0; ky < 5; ++ky) {
                const int q = r - ky;
                if (q >= 0 && q < 8)
                    acc[q] = __builtin_amdgcn_mfma_f32_16x16x32_f16(
                        a[ky], bf, acc[q], 0, 0, 0);
            }
        }
        #pragma unroll
        for (int py = 0; py < 4; ++py) {
            #pragma unroll
            for (int e = 0; e < 4; ++e) {
                float t = fmaxf(acc[2 * py][e], acc[2 * py + 1][e]);
                t = fmaxf(t, __shfl_xor(t, 1, 64));
                if (s == 13 && n >= 12) t = 0.0f;
                colsum[py][e] += t;
                const int oc = g * 4 + e;
                if (s == 0) {
                    const float c0 = GSHFL(t, 0), c1 = GSHFL(t, 2);
                    const float c2 = GSHFL(t, 4), c3 = GSHFL(t, 6);
                    const float S1 = c0, S2 = S1 + c1, S3 = S2 + c2, S4 = S3 + c3;
                    const float sv = (n == 0) ? S1 : (n == 1) ? S2
                                   : (n == 2) ? S3 : S4;
                    if (n < 4 && oc < C1) edgeLo[py][oc][n] = sv;
                }
                if (s == 13) {
                    const float d109 = GSHFL(t, 10), d108 = GSHFL(t, 8);
                    const float d107 = GSHFL(t, 6),  d106 = GSHFL(t, 4);
                    const float U1 = d109, U2 = U1 + d108, U3 = U2 + d107,
                                U4 = U3 + d106;
                    const float uv = (n == 0) ? U1 : (n == 1) ? U2
                                   : (n == 2) ? U3 : U4;
                    if (n < 4 && oc < C1) edgeHi[py][oc][n] = uv;
                }
            }
        }
    }
    #pragma unroll
    for (int py = 0; py < 4; ++py) {
        #pragma unroll
        for (int e = 0; e < 4; ++e) {
            float v = colsum[py][e];
            v += __shfl_xor(v, 2, 64);
            v += __shfl_xor(v, 4, 64);
            v += __shfl_xor(v, 8, 64);
            const int oc = g * 4 + e;
            if (n == 0 && oc < C1) rowR[wid][oc][py] = v;
        }
    }
    __syncthreads();
    if (tid < 150) {
        const int oc = tid / 25;
        const int rem = tid - oc * 25;
        const int ky = rem / 5, kx = rem - ky * 5;
        float total = 0.0f;
        #pragma unroll
        for (int py = 0; py < 4; ++py) {
            const int y = chunk * 4 + py;
            const bool valid = (y < P1) && ((unsigned)(y - ky) <= 105u);
            float v = rowR[0][oc][py] + rowR[1][oc][py] + rowR[2][oc][py]
                    + rowR[3][oc][py] + rowR[4][oc][py] + rowR[5][oc][py]
                    + rowR[6][oc][py];
            if (kx > 0) v -= edgeLo[py][oc][kx - 1];
            if (kx < 4) v -= edgeHi[py][oc][3 - kx];
            total += valid ? v : 0.0f;
        }
        partial[((size_t)b * NCHUNK + chunk) * PSTRIDE + tid] = total;
    }
}

__global__ __launch_bounds__(640) void k3_sample_pool_nchw(
    const float* __restrict__ x, const float* __restrict__ ltp,
    const float* __restrict__ wt, float* __restrict__ out)
{
    __shared__ float part[3 * Wg];
    const int L = blockIdx.x;
    const int q = L >> 3;
    const int h = q & 31;
    const int b = (L & 7) + 8 * (q >> 5);
    const int tid = threadIdx.x;

    const float w0 = wt[b * 2 + 0];
    const float w1 = wt[b * 2 + 1];
    const float l0 = ltp[b * 2 + 0];
    const float l1 = ltp[b * 2 + 1];
    const float start = logf(0.01f * w0);
    const float stop  = logf(0.6f  * w1);
    const float dr = stop - start;
    const float angle = 6.283185307179586f * (float)tid / (float)Wg;
    const float sn = __sinf(angle);
    const float cs = __cosf(angle);
    const float* xb = x + (size_t)b * Cn * PLANE;

    float acc0 = 0.0f, acc1 = 0.0f, acc2 = 0.0f;
    #pragma unroll
    for (int i = 0; i < UPR; ++i) {
        const float ri = __expf(start + dr * ((float)(h * UPR + i)
                                              * (1.0f / (float)(Hg - 1))));
        int x0, y0; float wx, wy;
        sample_coords(ri * sn + l0, ri * cs + l1, x0, y0, wx, wy);
        const float wx0 = 1.0f - wx, wy0 = 1.0f - wy;
        const float w00 = wx0 * wy0, w01 = wx * wy0;
        const float w10 = wx0 * wy,  w11 = wx * wy;
        const int o00 = y0 * IMG + x0;
        acc0 += w00*xb[o00] + w01*xb[o00+1] + w10*xb[o00+IMG] + w11*xb[o00+IMG+1];
        const float* x1p = xb + PLANE;
        acc1 += w00*x1p[o00] + w01*x1p[o00+1] + w10*x1p[o00+IMG] + w11*x1p[o00+IMG+1];
        const float* x2p = xb + 2 * PLANE;
        acc2 += w00*x2p[o00] + w01*x2p[o00+1] + w10*x2p[o00+IMG] + w11*x2p[o00+IMG+1];
    }
    part[0 * Wg + tid] = acc0;
    part[1 * Wg + tid] = acc1;
    part[2 * Wg + tid] = acc2;
    __syncthreads();

    if (tid < Cn * Ww) {
        const int c = tid / Ww;
        const int w = tid % Ww;
        const float* p = part + c * Wg + w * UPT;
        float s = 0.0f;
        #pragma unroll
        for (int j = 0; j < UPT; ++j) s += p[j];
        out[(((size_t)b * Cn + c) * Hh + h) * Ww + w] = s * (1.0f / (UPR * UPT));
    }
}

// -------------------------------------------------------------------------
extern "C" void kernel_launch(void* const* d_in, const int* in_sizes, int n_in,
                              void* d_out, int out_size, void* d_ws, size_t ws_size,
                              hipStream_t stream) {
    const float* x       = (const float*)d_in[0];
    const float* ltp     = (const float*)d_in[1];
    const float* conv1_w = (const float*)d_in[2];
    const float* conv1_b = (const float*)d_in[3];
    const float* conv2_w = (const float*)d_in[4];
    const float* conv2_b = (const float*)d_in[5];
    const float* fc1_w   = (const float*)d_in[6];
    const float* fc1_b   = (const float*)d_in[7];
    const float* fc2_w   = (const float*)d_in[8];
    const float* fc2_b   = (const float*)d_in[9];
    float* out = (float*)d_out;

    const int do_pack = (ws_size >= WS_NEEDED) ? 1 : 0;

    float* part_ws = (float*)d_ws;                  // B*28*PSTRIDE
    float* wt_ws   = part_ws + WT_OFF;              // B*2
    u16*   af      = (u16*)(part_ws + AF_OFF_F);    // 5*64*8 f16
    float* sctab   = part_ws + SC_OFF_F;            // 640*2
    float* radii   = part_ws + RAD_OFF_F;           // B*320
    u16*   x4h     = (u16*)(part_ws + X4H_OFF_F);   // 16B-aligned

    if (do_pack) {
        k0_prep<<<dim3(1), dim3(64), 0, stream>>>(conv1_w, af, sctab);
        kA_pack<<<dim3(Bn * PLANE / 4 / 256), dim3(256), 0, stream>>>(x, x4h);
        kB_conv<<<dim3(Bn, NCHUNK), dim3(TPB1), 0, stream>>>(
            x4h, af, conv1_b, part_ws);
        k2_head<<<dim3(Bn), dim3(256), 0, stream>>>(
            part_ws, conv2_w, conv2_b, fc1_w, fc1_b, fc2_w, fc2_b, ltp,
            wt_ws, radii, out);
        k3_sample<<<dim3(Hh * Bn), dim3(Wg), 0, stream>>>(
            x4h, ltp, sctab, radii, out);
    } else {
        k1_legacy<<<dim3(Bn, NCHUNK), dim3(TPB1), 0, stream>>>(
            x, conv1_w, conv1_b, part_ws);
        k2_head<<<dim3(Bn), dim3(256), 0, stream>>>(
            part_ws, conv2_w, conv2_b, fc1_w, fc1_b, fc2_w, fc2_b, ltp,
            wt_ws, radii, out);
        k3_sample_pool_nchw<<<dim3(Hh * Bn), dim3(Wg), 0, stream>>>(
            x, ltp, wt_ws, out);
    }
}

// Round 11
// 170.332 us; speedup vs baseline: 1.0204x; 1.0204x over previous
//
#include <hip/hip_runtime.h>
#include <math.h>

// Problem constants
#define Bn    64
#define Cn    3
#define IMG   224
#define PLANE (IMG*IMG)      // 50176
#define C1    6
#define P1    110            // conv1(220) + maxpool2 -> 110
#define NVALID (106*106)     // 11236
#define Hh    32
#define Ww    64
#define UPR   10
#define UPT   10
#define Hg    (Hh*UPR)       // 320
#define Wg    (Ww*UPT)       // 640
#define POOLED_SIZE (Bn*Cn*Hh*Ww)   // 393216
#define NCHUNK 28            // 28 chunks x 4 pooled rows = 112 >= 110
#define PSTRIDE 152          // padded 150-float partial slot
#define ROWB  (IMG*8)        // 1792 B: one NHWC4-f16 row
#define TPB1  448            // 7 waves: 14 strips / 7 = 2 each

typedef unsigned short u16;
typedef unsigned int u32;
typedef unsigned long long ull;
typedef _Float16 h8v __attribute__((ext_vector_type(8)));   // 8 f16 MFMA frag
typedef _Float16 h2v __attribute__((ext_vector_type(2)));   // half2 for dot2
typedef float f4v __attribute__((ext_vector_type(4)));      // 16x16 MFMA acc

// workspace: partials | wt | af | sincos tab | radii | x4h (f16 NHWC4)
#define PART_FLOATS ((size_t)Bn * NCHUNK * PSTRIDE)     // 272,384
#define WT_OFF      PART_FLOATS                         // 272,384 (128 f)
#define AF_OFF_F    (PART_FLOATS + Bn * 2)              // 272,512 (1280 f)
#define SC_OFF_F    (AF_OFF_F + 1280)                   // 273,792 (1280 f)
#define RAD_OFF_F   (SC_OFF_F + 1280)                   // 275,072 (20480 f)
#define X4H_OFF_F   (RAD_OFF_F + (size_t)Bn * Hg)       // 295,552 (byte%16==0)
#define X4B_U16     ((size_t)Bn * PLANE * 4)
#define WS_NEEDED   ((size_t)X4H_OFF_F * 4 + X4B_U16 * 2)

__device__ __forceinline__ unsigned hpack(float a, float b) {
    union { _Float16 h; u16 u; } x, y;
    x.h = (_Float16)a; y.h = (_Float16)b;
    return (unsigned)x.u | ((unsigned)y.u << 16);
}
__device__ __forceinline__ u16 f16b(float f) {
    union { _Float16 h; u16 u; } c; c.h = (_Float16)f; return c.u;
}
__device__ __forceinline__ float h2lo(unsigned v) {
    union { _Float16 h; u16 u; } c; c.u = (u16)(v & 0xffffu); return (float)c.h;
}
__device__ __forceinline__ float h2hi(unsigned v) {
    union { _Float16 h; u16 u; } c; c.u = (u16)(v >> 16); return (float)c.h;
}
// mixed-precision dot2: f16x2 * f16x2 accumulated into f32 (v_dot2_f32_f16)
__device__ __forceinline__ float fdot2u(u32 v, h2v w, float acc) {
    union { u32 u; h2v h; } c; c.u = v;
    return __builtin_amdgcn_fdot2(c.h, w, acc, false);
}

// group-local broadcast: read lane (group_base + idx) of a 16-lane group
#define GSHFL(v, idx) __shfl((v), (lane & 48) + (idx), 64)

// -------------------------------------------------------------------------
// KA: streaming fp32 NCHW -> f16 NHWC4 pack (read 25.7MB, write 12.9MB at
// memcpy-class BW). Block 3136 instead does the one-off prep (MFMA A-frags,
// k = ic+4*kx, + the 640-entry sin/cos table) — k0 folded in, one launch
// fewer.
// -------------------------------------------------------------------------
__global__ __launch_bounds__(256) void kA_pack(
    const float* __restrict__ x, u16* __restrict__ x4h,
    const float* __restrict__ w1, u16* __restrict__ af,
    float* __restrict__ sctab)
{
    const int tid = threadIdx.x;
    if (blockIdx.x == 3136) {             // prep block
        if (tid < 64) {
            const int n = tid & 15, g = tid >> 4;
            #pragma unroll
            for (int ky = 0; ky < 5; ++ky) {
                #pragma unroll
                for (int j = 0; j < 8; ++j) {
                    const int k = g * 8 + j, ic = k & 3, kx = k >> 2;
                    float w = 0.0f;
                    if (n < C1 && ic < 3 && kx < 5)
                        w = w1[((n * 3 + ic) * 5 + ky) * 5 + kx];
                    af[(ky * 64 + tid) * 8 + j] = f16b(w);
                }
            }
        }
        for (int t = tid; t < Wg; t += 256) {
            const float angle = 6.283185307179586f * (float)t / (float)Wg;
            sctab[t * 2 + 0] = sinf(angle);
            sctab[t * 2 + 1] = cosf(angle);
        }
        return;
    }

    const int i = blockIdx.x * 256 + tid;   // 0..802815
    const int b  = i / (PLANE / 4);
    const int p4 = i - b * (PLANE / 4);
    const float* xb = x + (size_t)b * 3 * PLANE + p4 * 4;
    const float4 c0 = *(const float4*)(xb);
    const float4 c1 = *(const float4*)(xb + PLANE);
    const float4 c2 = *(const float4*)(xb + 2 * PLANE);
    uint4 W0, W1;
    W0.x = hpack(c0.x, c1.x);  W0.y = hpack(c2.x, 0.0f);
    W0.z = hpack(c0.y, c1.y);  W0.w = hpack(c2.y, 0.0f);
    W1.x = hpack(c0.z, c1.z);  W1.y = hpack(c2.z, 0.0f);
    W1.z = hpack(c0.w, c1.w);  W1.w = hpack(c2.w, 0.0f);
    u16* ob = x4h + ((size_t)b * PLANE + p4 * 4) * 4;
    *(uint4*)(ob)     = W0;
    *(uint4*)(ob + 8) = W1;
}

// -------------------------------------------------------------------------
// KB: conv1 via MFMA with ASYNC global->LDS staging (global_load_lds x16B).
// R9-verified: dropped conv out of the top-5 (<42us vs 58-67 for all prior
// variants). Conv/pool/window-sum body identical to R5.
// -------------------------------------------------------------------------
__global__ __launch_bounds__(TPB1) void kB_conv(
    const u16* __restrict__ x4h,      // (B,224,224,4) f16
    const u16* __restrict__ af,       // prebuilt A-frags (5,64,8) f16
    const float* __restrict__ b1f,    // (6,)
    float* __restrict__ partial)      // (B,28,PSTRIDE)
{
    __shared__ __attribute__((aligned(16))) unsigned char xs[12 * ROWB];
    __shared__ float rowR[7][C1][4];
    __shared__ float edgeLo[4][C1][4];
    __shared__ float edgeHi[4][C1][4];

    const int b     = blockIdx.x;
    const int chunk = blockIdx.y;
    const int tid   = threadIdx.x;
    const int wid   = tid >> 6;
    const int lane  = tid & 63;
    const int n     = lane & 15;
    const int g     = lane >> 4;
    const int gy0   = chunk * 8;

    // tail chunk 27: only 8 valid rows (gy 216..223); zero LDS rows 8..11
    const int nInst = (chunk == NCHUNK - 1) ? 14 : 21;   // 1024B insts
    if (chunk == NCHUNK - 1)
        *(uint4*)(xs + 8 * ROWB + tid * 16) = (uint4){0u, 0u, 0u, 0u};

    // issue async copies: wave w owns insts {3w, 3w+1, 3w+2}
    {
        const char* gbase = (const char*)x4h
                          + ((size_t)b * PLANE + (size_t)gy0 * IMG) * 8;
        #pragma unroll
        for (int k = 0; k < 3; ++k) {
            const int j = wid * 3 + k;            // wave-uniform
            if (j < nInst) {
                const char* gp = gbase + j * 1024 + lane * 16;
                __builtin_amdgcn_global_load_lds(
                    (const __attribute__((address_space(1))) u32*)gp,
                    (__attribute__((address_space(3))) u32*)(xs + j * 1024),
                    16, 0, 0);
            }
        }
    }

    // A-frags (coalesced 16B loads, overlap with in-flight copies) + bias
    h8v a[5];
    #pragma unroll
    for (int ky = 0; ky < 5; ++ky)
        a[ky] = *(const h8v*)(af + (ky * 64 + lane) * 8);
    f4v binit;
    #pragma unroll
    for (int e = 0; e < 4; ++e) {
        const int oc = g * 4 + e;
        binit[e] = (oc < C1) ? b1f[oc] : 0.0f;
    }

    __syncthreads();   // drains vmcnt -> xs ready

    float colsum[4][4];
    #pragma unroll
    for (int py = 0; py < 4; ++py)
        #pragma unroll
        for (int e = 0; e < 4; ++e) colsum[py][e] = 0.0f;

    #pragma unroll
    for (int si = 0; si < 2; ++si) {
        const int s = wid * 2 + si;         // strip: conv cols s*16..s*16+15
        const unsigned sByte = (unsigned)(s * 128 + n * 8 + g * 16);

        f4v acc[8];
        #pragma unroll
        for (int q = 0; q < 8; ++q) acc[q] = binit;

        #pragma unroll
        for (int r = 0; r < 12; ++r) {
            h8v bf;
            const unsigned char* bp = xs + r * ROWB + sByte;
            ((ull*)&bf)[0] = *(const ull*)bp;
            ((ull*)&bf)[1] = *(const ull*)(bp + 8);
            #pragma unroll
            for (int ky = 0; ky < 5; ++ky) {
                const int q = r - ky;
                if (q >= 0 && q < 8)
                    acc[q] = __builtin_amdgcn_mfma_f32_16x16x32_f16(
                        a[ky], bf, acc[q], 0, 0, 0);
            }
        }

        // maxpool 2x2 + edge capture + col accumulation
        #pragma unroll
        for (int py = 0; py < 4; ++py) {
            #pragma unroll
            for (int e = 0; e < 4; ++e) {
                float t = fmaxf(acc[2 * py][e], acc[2 * py + 1][e]);
                t = fmaxf(t, __shfl_xor(t, 1, 64));
                if (s == 13 && n >= 12) t = 0.0f;     // junk cols 110,111
                colsum[py][e] += t;
                const int oc = g * 4 + e;
                if (s == 0) {                          // pooled cols 0..3
                    const float c0 = GSHFL(t, 0), c1 = GSHFL(t, 2);
                    const float c2 = GSHFL(t, 4), c3 = GSHFL(t, 6);
                    const float S1 = c0, S2 = S1 + c1, S3 = S2 + c2, S4 = S3 + c3;
                    const float sv = (n == 0) ? S1 : (n == 1) ? S2
                                   : (n == 2) ? S3 : S4;
                    if (n < 4 && oc < C1) edgeLo[py][oc][n] = sv;
                }
                if (s == 13) {                         // pooled cols 106..109
                    const float d109 = GSHFL(t, 10), d108 = GSHFL(t, 8);
                    const float d107 = GSHFL(t, 6),  d106 = GSHFL(t, 4);
                    const float U1 = d109, U2 = U1 + d108, U3 = U2 + d107,
                                U4 = U3 + d106;
                    const float uv = (n == 0) ? U1 : (n == 1) ? U2
                                   : (n == 2) ? U3 : U4;
                    if (n < 4 && oc < C1) edgeHi[py][oc][n] = uv;
                }
            }
        }
    }

    // per-wave row sums
    #pragma unroll
    for (int py = 0; py < 4; ++py) {
        #pragma unroll
        for (int e = 0; e < 4; ++e) {
            float v = colsum[py][e];
            v += __shfl_xor(v, 2, 64);
            v += __shfl_xor(v, 4, 64);
            v += __shfl_xor(v, 8, 64);
            const int oc = g * 4 + e;
            if (n == 0 && oc < C1) rowR[wid][oc][py] = v;
        }
    }
    __syncthreads();

    // final: slot(oc,ky,kx) = sum_py valid(py,ky) * (rowsum - S_kx - U_{4-kx})
    if (tid < 150) {
        const int oc = tid / 25;
        const int rem = tid - oc * 25;
        const int ky = rem / 5, kx = rem - ky * 5;
        float total = 0.0f;
        #pragma unroll
        for (int py = 0; py < 4; ++py) {
            const int y = chunk * 4 + py;
            const bool valid = (y < P1) && ((unsigned)(y - ky) <= 105u);
            float v = rowR[0][oc][py] + rowR[1][oc][py] + rowR[2][oc][py]
                    + rowR[3][oc][py] + rowR[4][oc][py] + rowR[5][oc][py]
                    + rowR[6][oc][py];
            if (kx > 0) v -= edgeLo[py][oc][kx - 1];
            if (kx < 4) v -= edgeHi[py][oc][3 - kx];
            total += valid ? v : 0.0f;
        }
        partial[((size_t)b * NCHUNK + chunk) * PSTRIDE + tid] = total;
    }
}

// -------------------------------------------------------------------------
// K2: head (wsum -> feat -> fc1 -> fc2 -> wt) AND the full 320-entry radii
// table per image. All transcendentals live here (64 blocks), not in k3.
// -------------------------------------------------------------------------
__global__ __launch_bounds__(256) void k2_head(
    const float* __restrict__ partial, const float* __restrict__ w2,
    const float* __restrict__ b2, const float* __restrict__ fc1w,
    const float* __restrict__ fc1b, const float* __restrict__ fc2w,
    const float* __restrict__ fc2b, const float* __restrict__ ltp,
    float* __restrict__ wt_ws, float* __restrict__ radii,
    float* __restrict__ out)
{
    const int b = blockIdx.x;
    const int tid = threadIdx.x;
    __shared__ float wsb[150];
    __shared__ float sfeat[16];
    __shared__ float sh[8];
    __shared__ float sSS[2];          // start, dr

    if (tid < 150) {
        const float* p = partial + (size_t)b * NCHUNK * PSTRIDE + tid;
        float s = 0.0f;
        #pragma unroll
        for (int c = 0; c < NCHUNK; ++c) s += p[c * PSTRIDE];
        wsb[tid] = s;
    }
    __syncthreads();
    if (tid < 16) {
        float s = 0.0f;
        for (int j = 0; j < 150; ++j) s += w2[tid * 150 + j] * wsb[j];
        sfeat[tid] = b2[tid] + s * (1.0f / (float)NVALID);
    }
    __syncthreads();
    if (tid < 8) {
        float s = fc1b[tid];
        #pragma unroll
        for (int j = 0; j < 16; ++j) s += fc1w[tid * 16 + j] * sfeat[j];
        sh[tid] = fmaxf(s, 0.0f);
    }
    __syncthreads();
    if (tid < 2) {
        float s = fc2b[tid];
        #pragma unroll
        for (int j = 0; j < 8; ++j) s += fc2w[tid * 8 + j] * sh[j];
        float sig = (s >= 0.0f) ? (1.0f / (1.0f + expf(-s)))
                                : (expf(s) / (1.0f + expf(s)));
        const float wgt = 5.0f * sig;
        wt_ws[b * 2 + tid] = wgt;
        out[POOLED_SIZE + b * 2 + tid] = wgt;
    }
    __syncthreads();
    if (tid == 0) {
        const float start = logf(0.01f * wt_ws[b * 2 + 0]);
        const float stop  = logf(0.6f  * wt_ws[b * 2 + 1]);
        sSS[0] = start; sSS[1] = stop - start;
    }
    __syncthreads();
    {
        const float start = sSS[0], dr = sSS[1];
        #pragma unroll
        for (int k = 0; k < 2; ++k) {
            const int t = tid + k * 256;
            if (t < Hg)
                radii[(size_t)b * Hg + t] =
                    expf(start + dr * ((float)t * (1.0f / (float)(Hg - 1))));
        }
    }
}

// -------------------------------------------------------------------------
// Clamp-coordinate sampling (equivalent to corner-clamp border mode).
// -------------------------------------------------------------------------
__device__ __forceinline__ void sample_coords(
    float gxn, float gyn, int& x0, int& y0, float& wx, float& wy)
{
    float ix = ((gxn + 1.0f) * (float)IMG - 1.0f) * 0.5f;
    float iy = ((gyn + 1.0f) * (float)IMG - 1.0f) * 0.5f;
    ix = fminf(fmaxf(ix, 0.0f), (float)(IMG - 1));
    iy = fminf(fmaxf(iy, 0.0f), (float)(IMG - 1));
    x0 = (int)ix; if (x0 > IMG - 2) x0 = IMG - 2;
    y0 = (int)iy; if (y0 > IMG - 2) y0 = IMG - 2;
    wx = ix - (float)x0;
    wy = iy - (float)y0;
}

// -------------------------------------------------------------------------
// K3 (f16 NHWC4, table-driven + dot2 interpolation): no transcendentals,
// no head. R11: bilinear blend via v_perm_b32 (pair the two x-taps' f16
// channel values in one reg) + v_dot2_f32_f16 (f16xf16 multiply, f32
// accumulate) — 6 perm + 6 dot2 per sample replaces 12 cvt + 12 FMA.
// Weights packed RNE (bias-free). 5-sample gather batches (10 loads in
// flight, VGPR low -> 3 blocks/CU). XCD-affinity: b = (L&7)+8*(q>>5).
// -------------------------------------------------------------------------
__global__ __launch_bounds__(640) void k3_sample(
    const u16* __restrict__ x4h,      // (B,224,224,4) f16
    const float* __restrict__ ltp,
    const float* __restrict__ sctab,  // (640,2) sin/cos
    const float* __restrict__ radii,  // (B,320)
    float* __restrict__ out)
{
    __shared__ float part[3 * Wg];

    const int L = blockIdx.x;         // 0..2047
    const int q = L >> 3;             // 0..255
    const int h = q & 31;
    const int b = (L & 7) + 8 * (q >> 5);
    const int tid = threadIdx.x;

    const float l0 = ltp[b * 2 + 0];
    const float l1 = ltp[b * 2 + 1];
    const float2 sc = *(const float2*)(sctab + tid * 2);
    const float sn = sc.x, cs = sc.y;

    const float* rad = radii + (size_t)b * Hg + h * UPR;
    const u16* xb4 = x4h + (size_t)b * PLANE * 4;

    int xi[UPR], yi[UPR];
    float wxa[UPR], wya[UPR];
    #pragma unroll
    for (int i = 0; i < UPR; ++i) {
        const float ri = rad[i];      // block-uniform (s_load broadcast)
        sample_coords(ri * sn + l0, ri * cs + l1, xi[i], yi[i], wxa[i], wya[i]);
    }

    float acc0 = 0.0f, acc1 = 0.0f, acc2 = 0.0f;
    #pragma unroll
    for (int bb = 0; bb < 2; ++bb) {
        uint4 R0[5], R1[5];
        #pragma unroll
        for (int i = 0; i < 5; ++i) {           // 10 gathers in flight
            const int sI = bb * 5 + i;
            const u16* base = xb4 + ((size_t)(yi[sI] * IMG + xi[sI])) * 4;
            R0[i] = *(const uint4*)(base);      // px x0|x0+1, row y0
            R1[i] = *(const uint4*)(base + IMG * 4);  // row y0+1
        }
        #pragma unroll
        for (int i = 0; i < 5; ++i) {
            const int sI = bb * 5 + i;
            const float wx = wxa[sI], wy = wya[sI];
            const float wx0 = 1.0f - wx, wy0 = 1.0f - wy;
            h2v wA, wB;                          // RNE-packed f16 weights
            wA[0] = (_Float16)(wx0 * wy0); wA[1] = (_Float16)(wx * wy0);
            wB[0] = (_Float16)(wx0 * wy);  wB[1] = (_Float16)(wx * wy);
            // ch0 = lo16 of (.x,.z); ch1 = hi16 of (.x,.z); ch2 = lo16 of (.y,.w)
            acc0 = fdot2u(__builtin_amdgcn_perm(R0[i].z, R0[i].x, 0x05040100u),
                          wA, acc0);
            acc0 = fdot2u(__builtin_amdgcn_perm(R1[i].z, R1[i].x, 0x05040100u),
                          wB, acc0);
            acc1 = fdot2u(__builtin_amdgcn_perm(R0[i].z, R0[i].x, 0x07060302u),
                          wA, acc1);
            acc1 = fdot2u(__builtin_amdgcn_perm(R1[i].z, R1[i].x, 0x07060302u),
                          wB, acc1);
            acc2 = fdot2u(__builtin_amdgcn_perm(R0[i].w, R0[i].y, 0x05040100u),
                          wA, acc2);
            acc2 = fdot2u(__builtin_amdgcn_perm(R1[i].w, R1[i].y, 0x05040100u),
                          wB, acc2);
        }
    }
    part[0 * Wg + tid] = acc0;
    part[1 * Wg + tid] = acc1;
    part[2 * Wg + tid] = acc2;
    __syncthreads();

    if (tid < Cn * Ww) {
        const int c = tid / Ww;
        const int w = tid % Ww;
        const float* p = part + c * Wg + w * UPT;
        float s = 0.0f;
        #pragma unroll
        for (int j = 0; j < UPT; ++j) s += p[j];
        out[(((size_t)b * Cn + c) * Hh + h) * Ww + w] = s * (1.0f / (UPR * UPT));
    }
}

// -------------------------------------------------------------------------
// Fallback path (ws too small): R6-style fp32-staged conv + fp32 sampling.
// -------------------------------------------------------------------------
__global__ __launch_bounds__(TPB1) void k1_legacy(
    const float* __restrict__ x, const float* __restrict__ w1,
    const float* __restrict__ b1, float* __restrict__ partial)
{
    __shared__ __attribute__((aligned(16))) unsigned char xs[12 * ROWB + 128];
    __shared__ __attribute__((aligned(16))) _Float16 sa[5][64][8];
    __shared__ float rowR[7][C1][4];
    __shared__ float edgeLo[4][C1][4];
    __shared__ float edgeHi[4][C1][4];

    const int b     = blockIdx.x;
    const int chunk = blockIdx.y;
    const int tid   = threadIdx.x;
    const int wid   = tid >> 6;
    const int lane  = tid & 63;
    const int n     = lane & 15;
    const int g     = lane >> 4;
    const int gy0   = chunk * 8;
    const float* xb = x + (size_t)b * (Cn * PLANE);

    if (wid == 0) {
        #pragma unroll
        for (int ky = 0; ky < 5; ++ky) {
            #pragma unroll
            for (int j = 0; j < 8; ++j) {
                const int kmem = g * 8 + j;
                const int ic = kmem & 3, kx = kmem >> 2;
                float w = 0.0f;
                if (n < C1 && ic < 3 && kx < 5)
                    w = w1[((n * 3 + ic) * 5 + ky) * 5 + kx];
                sa[ky][lane][j] = (_Float16)w;
            }
        }
    } else {
        for (int i = tid - 64; i < 12 * 112; i += TPB1 - 64) {
            const int r = i / 112;
            const int p = i - r * 112;
            const int gy = gy0 + r;
            uint4 U; U.x = U.y = U.z = U.w = 0u;
            if (gy < IMG) {
                const float2 v0 = *(const float2*)(xb + 0 * PLANE + gy * IMG + 2 * p);
                const float2 v1 = *(const float2*)(xb + 1 * PLANE + gy * IMG + 2 * p);
                const float2 v2 = *(const float2*)(xb + 2 * PLANE + gy * IMG + 2 * p);
                U.x = hpack(v0.x, v1.x);
                U.y = hpack(v2.x, 0.0f);
                U.z = hpack(v0.y, v1.y);
                U.w = hpack(v2.y, 0.0f);
            }
            *(uint4*)(xs + r * ROWB + p * 16) = U;
        }
    }
    __syncthreads();

    h8v a[5];
    #pragma unroll
    for (int ky = 0; ky < 5; ++ky) a[ky] = *(const h8v*)&sa[ky][lane][0];
    f4v binit;
    #pragma unroll
    for (int e = 0; e < 4; ++e) {
        const int oc = g * 4 + e;
        binit[e] = (oc < C1) ? b1[oc] : 0.0f;
    }

    float colsum[4][4];
    #pragma unroll
    for (int py = 0; py < 4; ++py)
        #pragma unroll
        for (int e = 0; e < 4; ++e) colsum[py][e] = 0.0f;

    #pragma unroll
    for (int si = 0; si < 2; ++si) {
        const int s = wid * 2 + si;
        const unsigned sByte = (unsigned)(s * 128 + n * 8 + g * 16);
        f4v acc[8];
        #pragma unroll
        for (int q = 0; q < 8; ++q) acc[q] = binit;
        #pragma unroll
        for (int r = 0; r < 12; ++r) {
            h8v bf;
            const unsigned char* bp = xs + r * ROWB + sByte;
            ((ull*)&bf)[0] = *(const ull*)bp;
            ((ull*)&bf)[1] = *(const ull*)(bp + 8);
            #pragma unroll
            for (int ky = 0; ky < 5; ++ky) {
                const int q = r - ky;
                if (q >= 0 && q < 8)
                    acc[q] = __builtin_amdgcn_mfma_f32_16x16x32_f16(
                        a[ky], bf, acc[q], 0, 0, 0);
            }
        }
        #pragma unroll
        for (int py = 0; py < 4; ++py) {
            #pragma unroll
            for (int e = 0; e < 4; ++e) {
                float t = fmaxf(acc[2 * py][e], acc[2 * py + 1][e]);
                t = fmaxf(t, __shfl_xor(t, 1, 64));
                if (s == 13 && n >= 12) t = 0.0f;
                colsum[py][e] += t;
                const int oc = g * 4 + e;
                if (s == 0) {
                    const float c0 = GSHFL(t, 0), c1 = GSHFL(t, 2);
                    const float c2 = GSHFL(t, 4), c3 = GSHFL(t, 6);
                    const float S1 = c0, S2 = S1 + c1, S3 = S2 + c2, S4 = S3 + c3;
                    const float sv = (n == 0) ? S1 : (n == 1) ? S2
                                   : (n == 2) ? S3 : S4;
                    if (n < 4 && oc < C1) edgeLo[py][oc][n] = sv;
                }
                if (s == 13) {
                    const float d109 = GSHFL(t, 10), d108 = GSHFL(t, 8);
                    const float d107 = GSHFL(t, 6),  d106 = GSHFL(t, 4);
                    const float U1 = d109, U2 = U1 + d108, U3 = U2 + d107,
                                U4 = U3 + d106;
                    const float uv = (n == 0) ? U1 : (n == 1) ? U2
                                   : (n == 2) ? U3 : U4;
                    if (n < 4 && oc < C1) edgeHi[py][oc][n] = uv;
                }
            }
        }
    }
    #pragma unroll
    for (int py = 0; py < 4; ++py) {
        #pragma unroll
        for (int e = 0; e < 4; ++e) {
            float v = colsum[py][e];
            v += __shfl_xor(v, 2, 64);
            v += __shfl_xor(v, 4, 64);
            v += __shfl_xor(v, 8, 64);
            const int oc = g * 4 + e;
            if (n == 0 && oc < C1) rowR[wid][oc][py] = v;
        }
    }
    __syncthreads();
    if (tid < 150) {
        const int oc = tid / 25;
        const int rem = tid - oc * 25;
        const int ky = rem / 5, kx = rem - ky * 5;
        float total = 0.0f;
        #pragma unroll
        for (int py = 0; py < 4; ++py) {
            const int y = chunk * 4 + py;
            const bool valid = (y < P1) && ((unsigned)(y - ky) <= 105u);
            float v = rowR[0][oc][py] + rowR[1][oc][py] + rowR[2][oc][py]
                    + rowR[3][oc][py] + rowR[4][oc][py] + rowR[5][oc][py]
                    + rowR[6][oc][py];
            if (kx > 0) v -= edgeLo[py][oc][kx - 1];
            if (kx < 4) v -= edgeHi[py][oc][3 - kx];
            total += valid ? v : 0.0f;
        }
        partial[((size_t)b * NCHUNK + chunk) * PSTRIDE + tid] = total;
    }
}

__global__ __launch_bounds__(640) void k3_sample_pool_nchw(
    const float* __restrict__ x, const float* __restrict__ ltp,
    const float* __restrict__ wt, float* __restrict__ out)
{
    __shared__ float part[3 * Wg];
    const int L = blockIdx.x;
    const int q = L >> 3;
    const int h = q & 31;
    const int b = (L & 7) + 8 * (q >> 5);
    const int tid = threadIdx.x;

    const float w0 = wt[b * 2 + 0];
    const float w1 = wt[b * 2 + 1];
    const float l0 = ltp[b * 2 + 0];
    const float l1 = ltp[b * 2 + 1];
    const float start = logf(0.01f * w0);
    const float stop  = logf(0.6f  * w1);
    const float dr = stop - start;
    const float angle = 6.283185307179586f * (float)tid / (float)Wg;
    const float sn = __sinf(angle);
    const float cs = __cosf(angle);
    const float* xb = x + (size_t)b * Cn * PLANE;

    float acc0 = 0.0f, acc1 = 0.0f, acc2 = 0.0f;
    #pragma unroll
    for (int i = 0; i < UPR; ++i) {
        const float ri = __expf(start + dr * ((float)(h * UPR + i)
                                              * (1.0f / (float)(Hg - 1))));
        int x0, y0; float wx, wy;
        sample_coords(ri * sn + l0, ri * cs + l1, x0, y0, wx, wy);
        const float wx0 = 1.0f - wx, wy0 = 1.0f - wy;
        const float w00 = wx0 * wy0, w01 = wx * wy0;
        const float w10 = wx0 * wy,  w11 = wx * wy;
        const int o00 = y0 * IMG + x0;
        acc0 += w00*xb[o00] + w01*xb[o00+1] + w10*xb[o00+IMG] + w11*xb[o00+IMG+1];
        const float* x1p = xb + PLANE;
        acc1 += w00*x1p[o00] + w01*x1p[o00+1] + w10*x1p[o00+IMG] + w11*x1p[o00+IMG+1];
        const float* x2p = xb + 2 * PLANE;
        acc2 += w00*x2p[o00] + w01*x2p[o00+1] + w10*x2p[o00+IMG] + w11*x2p[o00+IMG+1];
    }
    part[0 * Wg + tid] = acc0;
    part[1 * Wg + tid] = acc1;
    part[2 * Wg + tid] = acc2;
    __syncthreads();

    if (tid < Cn * Ww) {
        const int c = tid / Ww;
        const int w = tid % Ww;
        const float* p = part + c * Wg + w * UPT;
        float s = 0.0f;
        #pragma unroll
        for (int j = 0; j < UPT; ++j) s += p[j];
        out[(((size_t)b * Cn + c) * Hh + h) * Ww + w] = s * (1.0f / (UPR * UPT));
    }
}

// -------------------------------------------------------------------------
extern "C" void kernel_launch(void* const* d_in, const int* in_sizes, int n_in,
                              void* d_out, int out_size, void* d_ws, size_t ws_size,
                              hipStream_t stream) {
    const float* x       = (const float*)d_in[0];
    const float* ltp     = (const float*)d_in[1];
    const float* conv1_w = (const float*)d_in[2];
    const float* conv1_b = (const float*)d_in[3];
    const float* conv2_w = (const float*)d_in[4];
    const float* conv2_b = (const float*)d_in[5];
    const float* fc1_w   = (const float*)d_in[6];
    const float* fc1_b   = (const float*)d_in[7];
    const float* fc2_w   = (const float*)d_in[8];
    const float* fc2_b   = (const float*)d_in[9];
    float* out = (float*)d_out;

    const int do_pack = (ws_size >= WS_NEEDED) ? 1 : 0;

    float* part_ws = (float*)d_ws;                  // B*28*PSTRIDE
    float* wt_ws   = part_ws + WT_OFF;              // B*2
    u16*   af      = (u16*)(part_ws + AF_OFF_F);    // 5*64*8 f16
    float* sctab   = part_ws + SC_OFF_F;            // 640*2
    float* radii   = part_ws + RAD_OFF_F;           // B*320
    u16*   x4h     = (u16*)(part_ws + X4H_OFF_F);   // 16B-aligned

    if (do_pack) {
        kA_pack<<<dim3(Bn * PLANE / 4 / 256 + 1), dim3(256), 0, stream>>>(
            x, x4h, conv1_w, af, sctab);
        kB_conv<<<dim3(Bn, NCHUNK), dim3(TPB1), 0, stream>>>(
            x4h, af, conv1_b, part_ws);
        k2_head<<<dim3(Bn), dim3(256), 0, stream>>>(
            part_ws, conv2_w, conv2_b, fc1_w, fc1_b, fc2_w, fc2_b, ltp,
            wt_ws, radii, out);
        k3_sample<<<dim3(Hh * Bn), dim3(Wg), 0, stream>>>(
            x4h, ltp, sctab, radii, out);
    } else {
        k1_legacy<<<dim3(Bn, NCHUNK), dim3(TPB1), 0, stream>>>(
            x, conv1_w, conv1_b, part_ws);
        k2_head<<<dim3(Bn), dim3(256), 0, stream>>>(
            part_ws, conv2_w, conv2_b, fc1_w, fc1_b, fc2_w, fc2_b, ltp,
            wt_ws, radii, out);
        k3_sample_pool_nchw<<<dim3(Hh * Bn), dim3(Wg), 0, stream>>>(
            x, ltp, wt_ws, out);
    }
}